// Round 5
// baseline (508.798 us; speedup 1.0000x reference)
//
#include <hip/hip_runtime.h>
#include <math.h>
#include <stdint.h>

typedef unsigned short u16;
typedef unsigned int u32;

typedef __attribute__((ext_vector_type(8))) short bf16x8;
typedef __attribute__((ext_vector_type(4))) float f32x4;

#define ASYNC_COPY16(g, l)                                                         \
  __builtin_amdgcn_global_load_lds((__attribute__((address_space(1))) const void*)(g), \
                                   (__attribute__((address_space(3))) void*)(l), 16, 0, 0)

__device__ __forceinline__ float bf2f(u16 u) {
  union { u32 i; float f; } v; v.i = ((u32)u) << 16; return v.f;
}
__device__ __forceinline__ u16 f2bf(float f) {
  union { float f; u32 i; } v; v.f = f;
  u32 r = v.i + 0x7fffu + ((v.i >> 16) & 1u);
  return (u16)(r >> 16);
}

// ---------------------------------------------------------------------------
// K0: fused f32->bf16 conversion of all 4 weight tensors into ONE contiguous
// bf16 region (w1b | w2b | ew1b | ew2b).
// ---------------------------------------------------------------------------
__global__ __launch_bounds__(256) void cvt_all_k(
    const float* __restrict__ s0, const float* __restrict__ s1,
    const float* __restrict__ s2, const float* __restrict__ s3,
    u16* __restrict__ dst)
{
  const int64_t i0 = (int64_t)blockIdx.x * 2048 + (int64_t)threadIdx.x * 8;
  const float* src; int64_t rel;
  if (i0 < 2097152)       { src = s0; rel = i0; }
  else if (i0 < 4194304)  { src = s1; rel = i0 - 2097152; }
  else if (i0 < 20971520) { src = s2; rel = i0 - 4194304; }
  else                    { src = s3; rel = i0 - 20971520; }
  const float4 a = *(const float4*)(src + rel);
  const float4 b = *(const float4*)(src + rel + 4);
  union { u16 h[8]; uint4 v; } o;
  o.h[0] = f2bf(a.x); o.h[1] = f2bf(a.y); o.h[2] = f2bf(a.z); o.h[3] = f2bf(a.w);
  o.h[4] = f2bf(b.x); o.h[5] = f2bf(b.y); o.h[6] = f2bf(b.z); o.h[7] = f2bf(b.w);
  *(uint4*)(dst + i0) = o.v;
}

// ---------------------------------------------------------------------------
// K1: LayerNorm(x) + router logits + top-2. One block per token. No atomics.
// ---------------------------------------------------------------------------
__global__ __launch_bounds__(256) void ln_router_k(
    const float* __restrict__ x, const float* __restrict__ g, const float* __restrict__ b,
    const float* __restrict__ rw, const float* __restrict__ rb,
    u16* __restrict__ xn, int* __restrict__ tk_idx, float* __restrict__ tk_w)
{
  const int t = blockIdx.x, tid = threadIdx.x;
  __shared__ float xs[1024];
  __shared__ float red[8];
  __shared__ float logits[8];
  const int wave = tid >> 6, lane = tid & 63;

  const float4 xv = *(const float4*)(x + (size_t)t * 1024 + 4 * tid);
  float v0 = xv.x, v1 = xv.y, v2 = xv.z, v3 = xv.w;
  float s = v0 + v1 + v2 + v3;
  float q = v0 * v0 + v1 * v1 + v2 * v2 + v3 * v3;
#pragma unroll
  for (int o = 32; o > 0; o >>= 1) { s += __shfl_down(s, o, 64); q += __shfl_down(q, o, 64); }
  if (lane == 0) { red[wave] = s; red[4 + wave] = q; }
  __syncthreads();
  if (tid == 0) {
    float S = red[0] + red[1] + red[2] + red[3];
    float Q = red[4] + red[5] + red[6] + red[7];
    float mean = S * (1.0f / 1024.0f);
    float var = Q * (1.0f / 1024.0f) - mean * mean;
    red[0] = mean; red[1] = rsqrtf(var + 1e-5f);
  }
  __syncthreads();
  const float mean = red[0], rstd = red[1];
  float vv[4] = {v0, v1, v2, v3};
  union { u16 h[4]; uint2 v; } pk;
#pragma unroll
  for (int j = 0; j < 4; ++j) {
    int d = 4 * tid + j;
    float y = (vv[j] - mean) * rstd * g[d] + b[d];
    xs[d] = y;
    pk.h[j] = f2bf(y);
  }
  *(uint2*)(xn + (size_t)t * 1024 + 4 * tid) = pk.v;
  __syncthreads();
#pragma unroll
  for (int pe = 0; pe < 2; ++pe) {
    int e = wave + 4 * pe;
    const float* wrow = rw + (size_t)e * 1024;
    float acc = 0.f;
#pragma unroll
    for (int j = 0; j < 16; ++j) {
      int d = lane + 64 * j;
      acc += xs[d] * wrow[d];
    }
#pragma unroll
    for (int o = 32; o > 0; o >>= 1) acc += __shfl_down(acc, o, 64);
    if (lane == 0) logits[e] = acc + rb[e];
  }
  __syncthreads();
  if (tid == 0) {
    int i0 = 0; float l0 = logits[0];
#pragma unroll
    for (int e = 1; e < 8; ++e) if (logits[e] > l0) { l0 = logits[e]; i0 = e; }
    int i1 = -1; float l1 = -3.4e38f;
#pragma unroll
    for (int e = 0; e < 8; ++e) { if (e == i0) continue; if (logits[e] > l1) { l1 = logits[e]; i1 = e; } }
    float w0 = 1.0f / (1.0f + expf(l1 - l0));
    float w1 = 1.0f - w0;
    tk_idx[2 * t] = i0; tk_idx[2 * t + 1] = i1;
    tk_w[2 * t] = w0; tk_w[2 * t + 1] = w1;
  }
}

// ---------------------------------------------------------------------------
// K2: single-block deterministic slot assignment (atomic-free).
// ---------------------------------------------------------------------------
__device__ __forceinline__ uint4 u4_add(uint4 a, uint4 b) {
  uint4 r; r.x = a.x + b.x; r.y = a.y + b.y; r.z = a.z + b.z; r.w = a.w + b.w; return r;
}
__device__ __forceinline__ uint4 u4_sub(uint4 a, uint4 b) {
  uint4 r; r.x = a.x - b.x; r.y = a.y - b.y; r.z = a.z - b.z; r.w = a.w - b.w; return r;
}

__global__ __launch_bounds__(256) void assign_k(
    const int* __restrict__ tk_idx, const float* __restrict__ tk_w,
    int* __restrict__ offs, int* __restrict__ slot_token,
    float* __restrict__ slot_w, int* __restrict__ slot_of)
{
  const int tid = threadIdx.x, lane = tid & 63, wave = tid >> 6;
  int eidx[32];
#pragma unroll
  for (int j = 0; j < 32; ++j) eidx[j] = tk_idx[tid * 32 + j];

  uint4 p = {0u, 0u, 0u, 0u};
#pragma unroll
  for (int j = 0; j < 32; ++j) {
    int e = eidx[j];
    unsigned inc = 1u << ((e & 1) * 16);
    int c = e >> 1;
    if (c == 0) p.x += inc; else if (c == 1) p.y += inc;
    else if (c == 2) p.z += inc; else p.w += inc;
  }
  const uint4 own = p;
#pragma unroll
  for (int o = 1; o < 64; o <<= 1) {
    uint4 t;
    t.x = (u32)__shfl_up((int)p.x, o, 64);
    t.y = (u32)__shfl_up((int)p.y, o, 64);
    t.z = (u32)__shfl_up((int)p.z, o, 64);
    t.w = (u32)__shfl_up((int)p.w, o, 64);
    if (lane >= o) p = u4_add(p, t);
  }
  __shared__ uint4 wtot[4];
  __shared__ int offs_s[9];
  if (lane == 63) wtot[wave] = p;
  __syncthreads();
  uint4 wbase = {0u, 0u, 0u, 0u};
  uint4 gtot = {0u, 0u, 0u, 0u};
#pragma unroll
  for (int w2 = 0; w2 < 4; ++w2) {
    uint4 t = wtot[w2];
    if (w2 < wave) wbase = u4_add(wbase, t);
    gtot = u4_add(gtot, t);
  }
  const uint4 excl = u4_sub(p, own);
  if (tid == 0) {
    int gtots[8] = { (int)(gtot.x & 0xffff), (int)(gtot.x >> 16),
                     (int)(gtot.y & 0xffff), (int)(gtot.y >> 16),
                     (int)(gtot.z & 0xffff), (int)(gtot.z >> 16),
                     (int)(gtot.w & 0xffff), (int)(gtot.w >> 16) };
    int a = 0;
#pragma unroll
    for (int e = 0; e < 8; ++e) { offs_s[e] = a; offs[e] = a; a += gtots[e]; }
    offs_s[8] = a; offs[8] = a;
  }
  __syncthreads();
  const uint4 pre = u4_add(wbase, excl);
  int base[8];
  base[0] = offs_s[0] + (int)(pre.x & 0xffff);
  base[1] = offs_s[1] + (int)(pre.x >> 16);
  base[2] = offs_s[2] + (int)(pre.y & 0xffff);
  base[3] = offs_s[3] + (int)(pre.y >> 16);
  base[4] = offs_s[4] + (int)(pre.z & 0xffff);
  base[5] = offs_s[5] + (int)(pre.z >> 16);
  base[6] = offs_s[6] + (int)(pre.w & 0xffff);
  base[7] = offs_s[7] + (int)(pre.w >> 16);
#pragma unroll
  for (int j = 0; j < 32; ++j) {
    int idx = tid * 32 + j;
    int e = eidx[j];
    int s = base[e]++;
    slot_token[s] = idx >> 1;
    slot_w[s] = tk_w[idx];
    slot_of[idx] = s;
  }
}

// ---------------------------------------------------------------------------
// Fused NT GEMM over z = 0..8 (z=0 shared expert, z>0 routed segments).
// Round-5 structure: DOUBLE-BUFFERED single-barrier K-loop (prefetch tile
// k+1 during MFMA of tile k — the old 2-barrier loop paid full memory
// latency every iteration at 2-3 blocks/CU), and FRAGMENT-ORDER LDS layout
// (each 16-row i-tile stored [i][fq][fr]: ds_read_b128 addresses linear in
// lane -> zero bank conflicts; round-4 counter: 6.7M conflict cycles).
// Staging lane-map: wave w, lane L loads row (tile*16 + (L&15)), k-granule
// (L>>4) — same 64B-per-row global footprint, satisfies global_load_lds's
// wave-uniform-base + lane*16B rule.
// STAGE 1: A=x_norm (z>0 gathered via slot_token), out=GELU->bf16 hid.
// STAGE 2: A=hid (z>0 rows 4096+slot), out f32 * (z==0 ? 1/9 : slot_w).
// ---------------------------------------------------------------------------
template <int N, int KD, int STAGE>
__global__ __launch_bounds__(256) void gemm_fused_k(
    const u16* __restrict__ Abase, const u16* __restrict__ Bsh,
    const u16* __restrict__ Bex, const float* __restrict__ bias_sh,
    const float* __restrict__ bias_ex,
    float* __restrict__ outF, u16* __restrict__ outH,
    const int* __restrict__ offs, const int* __restrict__ slot_token,
    const float* __restrict__ slot_w)
{
  const int tid = threadIdx.x;
  const int wave = tid >> 6, lane = tid & 63;
  const int fr = lane & 15, fq = lane >> 4;
  const int z = blockIdx.z;
  int off = 0, cnt = 4096, obase = 0;
  const u16* B = Bsh;
  const float* biasp = bias_sh;
  if (z > 0) {
    off = offs[z - 1]; cnt = offs[z] - off; obase = 4096 + off;
    B = Bex + (size_t)(z - 1) * N * KD;
    biasp = bias_ex + (size_t)(z - 1) * N;
  }
  const int m0 = blockIdx.y * 128;
  if (m0 >= cnt) return;
  const int n0 = blockIdx.x * 128;

  // [buf][ A: 8 i-tiles x 512 | B: 8 n-tiles x 512 ]  (512 u16 = 1024 B/tile)
  __shared__ u16 lds[2][8192];

  // staging rows (fragment-order lane map)
  int rowA0 = m0 + wave * 16 + fr;      if (rowA0 > cnt - 1) rowA0 = cnt - 1;
  int rowA1 = m0 + 64 + wave * 16 + fr; if (rowA1 > cnt - 1) rowA1 = cnt - 1;
  size_t arow0, arow1;
  if (STAGE == 1) {
    if (z == 0) { arow0 = (size_t)rowA0; arow1 = (size_t)rowA1; }
    else        { arow0 = (size_t)slot_token[off + rowA0]; arow1 = (size_t)slot_token[off + rowA1]; }
  } else {
    if (z == 0) { arow0 = (size_t)rowA0; arow1 = (size_t)rowA1; }
    else        { arow0 = (size_t)(4096 + off + rowA0); arow1 = (size_t)(4096 + off + rowA1); }
  }
  const u16* gA0 = Abase + arow0 * KD + fq * 8;
  const u16* gA1 = Abase + arow1 * KD + fq * 8;
  const u16* gB0 = B + (size_t)(n0 + wave * 16 + fr) * KD + fq * 8;
  const u16* gB1 = B + (size_t)(n0 + 64 + wave * 16 + fr) * KD + fq * 8;

  const int wr = wave >> 1, wc = wave & 1;

  f32x4 acc[4][4];
  const f32x4 zero = {0.f, 0.f, 0.f, 0.f};
#pragma unroll
  for (int i = 0; i < 4; ++i)
#pragma unroll
    for (int n = 0; n < 4; ++n) acc[i][n] = zero;

  const int NK = KD / 32;
  // prefetch tile 0 into buffer 0
  {
    u16* nb = &lds[0][0];
    ASYNC_COPY16(gA0, nb + wave * 512);
    ASYNC_COPY16(gA1, nb + (4 + wave) * 512);
    ASYNC_COPY16(gB0, nb + 4096 + wave * 512);
    ASYNC_COPY16(gB1, nb + 4096 + (4 + wave) * 512);
    gA0 += 32; gA1 += 32; gB0 += 32; gB1 += 32;
  }

  for (int kb = 0; kb < NK; ++kb) {
    const int cur = kb & 1;
    __syncthreads();  // drains prefetch into cur; prior reads of nxt complete
    if (kb + 1 < NK) {
      u16* nb = &lds[cur ^ 1][0];
      ASYNC_COPY16(gA0, nb + wave * 512);
      ASYNC_COPY16(gA1, nb + (4 + wave) * 512);
      ASYNC_COPY16(gB0, nb + 4096 + wave * 512);
      ASYNC_COPY16(gB1, nb + 4096 + (4 + wave) * 512);
      gA0 += 32; gA1 += 32; gB0 += 32; gB1 += 32;
    }
    const u16* cb = &lds[cur][0];
    bf16x8 af[4], bfv[4];
#pragma unroll
    for (int i = 0; i < 4; ++i) af[i] = *(const bf16x8*)(cb + (wr * 4 + i) * 512 + lane * 8);
#pragma unroll
    for (int n = 0; n < 4; ++n) bfv[n] = *(const bf16x8*)(cb + 4096 + (wc * 4 + n) * 512 + lane * 8);
#pragma unroll
    for (int i = 0; i < 4; ++i)
#pragma unroll
      for (int n = 0; n < 4; ++n)
        acc[i][n] = __builtin_amdgcn_mfma_f32_16x16x32_bf16(af[i], bfv[n], acc[i][n], 0, 0, 0);
  }

  // epilogue: C/D layout col=lane&15, row=(lane>>4)*4+reg
  const int colBase = n0 + wc * 64;
#pragma unroll
  for (int i = 0; i < 4; ++i) {
    const int mlBase = m0 + wr * 64 + i * 16 + fq * 4;
#pragma unroll
    for (int r = 0; r < 4; ++r) {
      const int ml = mlBase + r;
      if (ml >= cnt) continue;
      const size_t orow = (size_t)(obase + ml) * N;
      float rwgt = (STAGE == 2) ? ((z == 0) ? (1.0f / 9.0f) : slot_w[off + ml]) : 1.f;
#pragma unroll
      for (int n = 0; n < 4; ++n) {
        const int col = colBase + n * 16 + fr;
        float v = acc[i][n][r] + biasp[col];
        if (STAGE == 1) {
          v = 0.5f * v * (1.0f + erff(v * 0.70710678118654752f));  // exact GELU
          outH[orow + col] = f2bf(v);
        } else {
          outF[orow + col] = v * rwgt;
        }
      }
    }
  }
}

// ---------------------------------------------------------------------------
// K5: combine shared + 2 expert slots, then LayerNorm over O. Block per token.
// ---------------------------------------------------------------------------
__global__ __launch_bounds__(256) void combine_ln2_k(
    const float* __restrict__ sh_out, const float* __restrict__ eout,
    const int* __restrict__ slot_of,
    const float* __restrict__ g2, const float* __restrict__ b2,
    float* __restrict__ out)
{
  const int t = blockIdx.x, tid = threadIdx.x;
  const int wave = tid >> 6, lane = tid & 63;
  __shared__ float red[8];
  const size_t s0 = (size_t)slot_of[2 * t], s1 = (size_t)slot_of[2 * t + 1];
  const float4 a  = *(const float4*)(sh_out + (size_t)t * 1024 + 4 * tid);
  const float4 c0 = *(const float4*)(eout + s0 * 1024 + 4 * tid);
  const float4 c1 = *(const float4*)(eout + s1 * 1024 + 4 * tid);
  float v0 = a.x + c0.x + c1.x;
  float v1 = a.y + c0.y + c1.y;
  float v2 = a.z + c0.z + c1.z;
  float v3 = a.w + c0.w + c1.w;
  float s = v0 + v1 + v2 + v3;
  float q = v0 * v0 + v1 * v1 + v2 * v2 + v3 * v3;
#pragma unroll
  for (int o = 32; o > 0; o >>= 1) { s += __shfl_down(s, o, 64); q += __shfl_down(q, o, 64); }
  if (lane == 0) { red[wave] = s; red[4 + wave] = q; }
  __syncthreads();
  if (tid == 0) {
    float S = red[0] + red[1] + red[2] + red[3];
    float Q = red[4] + red[5] + red[6] + red[7];
    float mean = S * (1.0f / 1024.0f);
    float var = Q * (1.0f / 1024.0f) - mean * mean;
    red[0] = mean; red[1] = rsqrtf(var + 1e-5f);
  }
  __syncthreads();
  const float mean = red[0], rstd = red[1];
  float vv[4] = {v0, v1, v2, v3};
#pragma unroll
  for (int j = 0; j < 4; ++j) {
    int d = 4 * tid + j;
    out[(size_t)t * 1024 + d] = (vv[j] - mean) * rstd * g2[d] + b2[d];
  }
}

// ---------------------------------------------------------------------------
extern "C" void kernel_launch(void* const* d_in, const int* in_sizes, int n_in,
                              void* d_out, int out_size, void* d_ws, size_t ws_size,
                              hipStream_t stream)
{
  const float* x     = (const float*)d_in[0];
  const float* ln1_g = (const float*)d_in[1];
  const float* ln1_b = (const float*)d_in[2];
  const float* rw    = (const float*)d_in[3];
  const float* rb    = (const float*)d_in[4];
  const float* sh_w1 = (const float*)d_in[5];
  const float* sh_b1 = (const float*)d_in[6];
  const float* sh_w2 = (const float*)d_in[7];
  const float* sh_b2 = (const float*)d_in[8];
  const float* e_w1  = (const float*)d_in[9];
  const float* e_b1  = (const float*)d_in[10];
  const float* e_w2  = (const float*)d_in[11];
  const float* e_b2  = (const float*)d_in[12];
  const float* ln2_g = (const float*)d_in[13];
  const float* ln2_b = (const float*)d_in[14];
  float* out = (float*)d_out;

  char* w = (char*)d_ws;
  u16*   x_norm = (u16*)(w + 0);              //  8 MiB  [4096,1024] bf16
  u16*   hid    = (u16*)(w + (8u << 20));     // 48 MiB  [12288,2048] bf16 (shared|slots)
  float* outb   = (float*)(w + (56u << 20));  // 48 MiB  [12288,1024] f32  (shared|slots)
  u16*   w1b    = (u16*)(w + (104u << 20));   //  4 MiB  [2048,1024]  (contig with below)
  u16*   w2b    = (u16*)(w + (108u << 20));   //  4 MiB  [1024,2048]
  u16*   ew1b   = (u16*)(w + (112u << 20));   // 32 MiB  [8,2048,1024]
  u16*   ew2b   = (u16*)(w + (144u << 20));   // 32 MiB  [8,1024,2048]
  char*  meta   = w + (176u << 20);
  int*   tk_idx     = (int*)(meta);
  float* tk_w       = (float*)(meta + (32u << 10));
  int*   slot_token = (int*)(meta + (64u << 10));
  float* slot_w     = (float*)(meta + (96u << 10));
  int*   slot_of    = (int*)(meta + (128u << 10));
  int*   offs       = (int*)(meta + (160u << 10)); // 9 ints

  // all weights f32 -> bf16 in one pass (dsts are contiguous from w1b)
  cvt_all_k<<<18432, 256, 0, stream>>>(sh_w1, sh_w2, e_w1, e_w2, w1b);

  ln_router_k<<<4096, 256, 0, stream>>>(x, ln1_g, ln1_b, rw, rb, x_norm, tk_idx, tk_w);
  assign_k<<<1, 256, 0, stream>>>(tk_idx, tk_w, offs, slot_token, slot_w, slot_of);

  // FC1 (shared z=0 + experts z=1..8): -> GELU -> hid bf16
  gemm_fused_k<2048, 1024, 1><<<dim3(16, 32, 9), 256, 0, stream>>>(
      x_norm, w1b, ew1b, sh_b1, e_b1, nullptr, hid, offs, slot_token, nullptr);
  // FC2 (shared z=0 + experts z=1..8): -> scaled f32 -> outb
  gemm_fused_k<1024, 2048, 2><<<dim3(8, 32, 9), 256, 0, stream>>>(
      hid, w2b, ew2b, sh_b2, e_b2, outb, nullptr, offs, slot_token, slot_w);

  combine_ln2_k<<<4096, 256, 0, stream>>>(outb, outb + (size_t)4096 * 1024,
                                          slot_of, ln2_g, ln2_b, out);
}

// Round 6
// 438.590 us; speedup vs baseline: 1.1601x; 1.1601x over previous
//
#include <hip/hip_runtime.h>
#include <math.h>
#include <stdint.h>

typedef unsigned short u16;
typedef unsigned int u32;

typedef __attribute__((ext_vector_type(8))) short bf16x8;
typedef __attribute__((ext_vector_type(4))) float f32x4;

#define ASYNC_COPY16(g, l)                                                         \
  __builtin_amdgcn_global_load_lds((__attribute__((address_space(1))) const void*)(g), \
                                   (__attribute__((address_space(3))) void*)(l), 16, 0, 0)

__device__ __forceinline__ float bf2f(u16 u) {
  union { u32 i; float f; } v; v.i = ((u32)u) << 16; return v.f;
}
__device__ __forceinline__ u16 f2bf(float f) {
  union { float f; u32 i; } v; v.f = f;
  u32 r = v.i + 0x7fffu + ((v.i >> 16) & 1u);
  return (u16)(r >> 16);
}
// fast GELU (tanh form via sigmoid): x*sigmoid(1.5957691*(x+0.044715*x^3))
// max |err| vs exact erf-GELU ~1e-3 -> ~2e-3 on final output (thr 0.109)
__device__ __forceinline__ float gelu_fast(float x) {
  float t = x * x;
  float z = 1.5957691f * x * (1.0f + 0.044715f * t);
  return x / (1.0f + __expf(-z));
}

// ---------------------------------------------------------------------------
// K0: fused f32->bf16 conversion of all 4 weight tensors into ONE contiguous
// bf16 region (w1b | w2b | ew1b | ew2b).
// ---------------------------------------------------------------------------
__global__ __launch_bounds__(256) void cvt_all_k(
    const float* __restrict__ s0, const float* __restrict__ s1,
    const float* __restrict__ s2, const float* __restrict__ s3,
    u16* __restrict__ dst)
{
  const int64_t i0 = (int64_t)blockIdx.x * 2048 + (int64_t)threadIdx.x * 8;
  const float* src; int64_t rel;
  if (i0 < 2097152)       { src = s0; rel = i0; }
  else if (i0 < 4194304)  { src = s1; rel = i0 - 2097152; }
  else if (i0 < 20971520) { src = s2; rel = i0 - 4194304; }
  else                    { src = s3; rel = i0 - 20971520; }
  const float4 a = *(const float4*)(src + rel);
  const float4 b = *(const float4*)(src + rel + 4);
  union { u16 h[8]; uint4 v; } o;
  o.h[0] = f2bf(a.x); o.h[1] = f2bf(a.y); o.h[2] = f2bf(a.z); o.h[3] = f2bf(a.w);
  o.h[4] = f2bf(b.x); o.h[5] = f2bf(b.y); o.h[6] = f2bf(b.z); o.h[7] = f2bf(b.w);
  *(uint4*)(dst + i0) = o.v;
}

// ---------------------------------------------------------------------------
// K1: LayerNorm(x) + router logits + top-2. One block per token. No atomics.
// ---------------------------------------------------------------------------
__global__ __launch_bounds__(256) void ln_router_k(
    const float* __restrict__ x, const float* __restrict__ g, const float* __restrict__ b,
    const float* __restrict__ rw, const float* __restrict__ rb,
    u16* __restrict__ xn, int* __restrict__ tk_idx, float* __restrict__ tk_w)
{
  const int t = blockIdx.x, tid = threadIdx.x;
  __shared__ float xs[1024];
  __shared__ float red[8];
  __shared__ float logits[8];
  const int wave = tid >> 6, lane = tid & 63;

  const float4 xv = *(const float4*)(x + (size_t)t * 1024 + 4 * tid);
  float v0 = xv.x, v1 = xv.y, v2 = xv.z, v3 = xv.w;
  float s = v0 + v1 + v2 + v3;
  float q = v0 * v0 + v1 * v1 + v2 * v2 + v3 * v3;
#pragma unroll
  for (int o = 32; o > 0; o >>= 1) { s += __shfl_down(s, o, 64); q += __shfl_down(q, o, 64); }
  if (lane == 0) { red[wave] = s; red[4 + wave] = q; }
  __syncthreads();
  if (tid == 0) {
    float S = red[0] + red[1] + red[2] + red[3];
    float Q = red[4] + red[5] + red[6] + red[7];
    float mean = S * (1.0f / 1024.0f);
    float var = Q * (1.0f / 1024.0f) - mean * mean;
    red[0] = mean; red[1] = rsqrtf(var + 1e-5f);
  }
  __syncthreads();
  const float mean = red[0], rstd = red[1];
  float vv[4] = {v0, v1, v2, v3};
  union { u16 h[4]; uint2 v; } pk;
#pragma unroll
  for (int j = 0; j < 4; ++j) {
    int d = 4 * tid + j;
    float y = (vv[j] - mean) * rstd * g[d] + b[d];
    xs[d] = y;
    pk.h[j] = f2bf(y);
  }
  *(uint2*)(xn + (size_t)t * 1024 + 4 * tid) = pk.v;
  __syncthreads();
#pragma unroll
  for (int pe = 0; pe < 2; ++pe) {
    int e = wave + 4 * pe;
    const float* wrow = rw + (size_t)e * 1024;
    float acc = 0.f;
#pragma unroll
    for (int j = 0; j < 16; ++j) {
      int d = lane + 64 * j;
      acc += xs[d] * wrow[d];
    }
#pragma unroll
    for (int o = 32; o > 0; o >>= 1) acc += __shfl_down(acc, o, 64);
    if (lane == 0) logits[e] = acc + rb[e];
  }
  __syncthreads();
  if (tid == 0) {
    int i0 = 0; float l0 = logits[0];
#pragma unroll
    for (int e = 1; e < 8; ++e) if (logits[e] > l0) { l0 = logits[e]; i0 = e; }
    int i1 = -1; float l1 = -3.4e38f;
#pragma unroll
    for (int e = 0; e < 8; ++e) { if (e == i0) continue; if (logits[e] > l1) { l1 = logits[e]; i1 = e; } }
    float w0 = 1.0f / (1.0f + expf(l1 - l0));
    float w1 = 1.0f - w0;
    tk_idx[2 * t] = i0; tk_idx[2 * t + 1] = i1;
    tk_w[2 * t] = w0; tk_w[2 * t + 1] = w1;
  }
}

// ---------------------------------------------------------------------------
// K2: single-block deterministic slot assignment (atomic-free).
// ---------------------------------------------------------------------------
__device__ __forceinline__ uint4 u4_add(uint4 a, uint4 b) {
  uint4 r; r.x = a.x + b.x; r.y = a.y + b.y; r.z = a.z + b.z; r.w = a.w + b.w; return r;
}
__device__ __forceinline__ uint4 u4_sub(uint4 a, uint4 b) {
  uint4 r; r.x = a.x - b.x; r.y = a.y - b.y; r.z = a.z - b.z; r.w = a.w - b.w; return r;
}

__global__ __launch_bounds__(256) void assign_k(
    const int* __restrict__ tk_idx, const float* __restrict__ tk_w,
    int* __restrict__ offs, int* __restrict__ slot_token,
    float* __restrict__ slot_w, int* __restrict__ slot_of)
{
  const int tid = threadIdx.x, lane = tid & 63, wave = tid >> 6;
  int eidx[32];
#pragma unroll
  for (int j = 0; j < 32; ++j) eidx[j] = tk_idx[tid * 32 + j];

  uint4 p = {0u, 0u, 0u, 0u};
#pragma unroll
  for (int j = 0; j < 32; ++j) {
    int e = eidx[j];
    unsigned inc = 1u << ((e & 1) * 16);
    int c = e >> 1;
    if (c == 0) p.x += inc; else if (c == 1) p.y += inc;
    else if (c == 2) p.z += inc; else p.w += inc;
  }
  const uint4 own = p;
#pragma unroll
  for (int o = 1; o < 64; o <<= 1) {
    uint4 t;
    t.x = (u32)__shfl_up((int)p.x, o, 64);
    t.y = (u32)__shfl_up((int)p.y, o, 64);
    t.z = (u32)__shfl_up((int)p.z, o, 64);
    t.w = (u32)__shfl_up((int)p.w, o, 64);
    if (lane >= o) p = u4_add(p, t);
  }
  __shared__ uint4 wtot[4];
  __shared__ int offs_s[9];
  if (lane == 63) wtot[wave] = p;
  __syncthreads();
  uint4 wbase = {0u, 0u, 0u, 0u};
  uint4 gtot = {0u, 0u, 0u, 0u};
#pragma unroll
  for (int w2 = 0; w2 < 4; ++w2) {
    uint4 t = wtot[w2];
    if (w2 < wave) wbase = u4_add(wbase, t);
    gtot = u4_add(gtot, t);
  }
  const uint4 excl = u4_sub(p, own);
  if (tid == 0) {
    int gtots[8] = { (int)(gtot.x & 0xffff), (int)(gtot.x >> 16),
                     (int)(gtot.y & 0xffff), (int)(gtot.y >> 16),
                     (int)(gtot.z & 0xffff), (int)(gtot.z >> 16),
                     (int)(gtot.w & 0xffff), (int)(gtot.w >> 16) };
    int a = 0;
#pragma unroll
    for (int e = 0; e < 8; ++e) { offs_s[e] = a; offs[e] = a; a += gtots[e]; }
    offs_s[8] = a; offs[8] = a;
  }
  __syncthreads();
  const uint4 pre = u4_add(wbase, excl);
  int base[8];
  base[0] = offs_s[0] + (int)(pre.x & 0xffff);
  base[1] = offs_s[1] + (int)(pre.x >> 16);
  base[2] = offs_s[2] + (int)(pre.y & 0xffff);
  base[3] = offs_s[3] + (int)(pre.y >> 16);
  base[4] = offs_s[4] + (int)(pre.z & 0xffff);
  base[5] = offs_s[5] + (int)(pre.z >> 16);
  base[6] = offs_s[6] + (int)(pre.w & 0xffff);
  base[7] = offs_s[7] + (int)(pre.w >> 16);
#pragma unroll
  for (int j = 0; j < 32; ++j) {
    int idx = tid * 32 + j;
    int e = eidx[j];
    int s = base[e]++;
    slot_token[s] = idx >> 1;
    slot_w[s] = tk_w[idx];
    slot_of[idx] = s;
  }
}

// ---------------------------------------------------------------------------
// Fused NT GEMM over z = 0..8 (z=0 shared expert, z>0 routed segments).
// Round-6 structure: round-4's COALESCED staging lane-map (lane L: row
// tid>>2, 16B granule tid&3 — adjacent lanes read one contiguous 64B row
// segment; round-5's scattered map dropped hbm_gbps 1180->885) + row-major
// LDS layout (bank conflicts accepted — m97 runs 874 TF with them), with a
// DOUBLE-BUFFERED single-barrier K-loop: prefetch tile k+1 issued right
// after the barrier, MFMAs of tile k cover its latency.
// STAGE 1: A=x_norm (z>0 gathered via slot_token), out = fast-GELU -> bf16.
// STAGE 2: A=hid (z>0 rows 4096+slot), out bf16 * (z==0 ? 1/9 : slot_w).
// Epilogue uses sigmoid-GELU (7 VALU ops vs ~35 for erff: round-4 FC1 spent
// comparable time in epilogue VALU as in the whole K-loop).
// ---------------------------------------------------------------------------
template <int N, int KD, int STAGE>
__global__ __launch_bounds__(256) void gemm_fused_k(
    const u16* __restrict__ Abase, const u16* __restrict__ Bsh,
    const u16* __restrict__ Bex, const float* __restrict__ bias_sh,
    const float* __restrict__ bias_ex,
    u16* __restrict__ outH,
    const int* __restrict__ offs, const int* __restrict__ slot_token,
    const float* __restrict__ slot_w)
{
  const int tid = threadIdx.x;
  const int z = blockIdx.z;
  int off = 0, cnt = 4096, obase = 0;
  const u16* B = Bsh;
  const float* biasp = bias_sh;
  if (z > 0) {
    off = offs[z - 1]; cnt = offs[z] - off; obase = 4096 + off;
    B = Bex + (size_t)(z - 1) * N * KD;
    biasp = bias_ex + (size_t)(z - 1) * N;
  }
  const int m0 = blockIdx.y * 128;
  if (m0 >= cnt) return;
  const int n0 = blockIdx.x * 128;

  __shared__ u16 lA[2][4096];
  __shared__ u16 lB[2][4096];

  const int rS = tid >> 2;          // staging row 0..63
  const int c8 = (tid & 3) * 8;     // staging col granule (8 bf16 = 16B)

  int ra0 = m0 + rS;      if (ra0 > cnt - 1) ra0 = cnt - 1;
  int ra1 = m0 + rS + 64; if (ra1 > cnt - 1) ra1 = cnt - 1;
  size_t arow0, arow1;
  if (STAGE == 1) {
    if (z == 0) { arow0 = (size_t)ra0; arow1 = (size_t)ra1; }
    else        { arow0 = (size_t)slot_token[off + ra0]; arow1 = (size_t)slot_token[off + ra1]; }
  } else {
    if (z == 0) { arow0 = (size_t)ra0; arow1 = (size_t)ra1; }
    else        { arow0 = (size_t)(4096 + off + ra0); arow1 = (size_t)(4096 + off + ra1); }
  }
  const u16* gA0 = Abase + arow0 * KD + c8;
  const u16* gA1 = Abase + arow1 * KD + c8;
  const u16* gB0 = B + (size_t)(n0 + rS) * KD + c8;
  const u16* gB1 = B + (size_t)(n0 + rS + 64) * KD + c8;

  const int wave = tid >> 6, lane = tid & 63;
  const int wr = wave >> 1, wc = wave & 1;
  const int fr = lane & 15, fq = lane >> 4;

  f32x4 acc[4][4];
  const f32x4 zero = {0.f, 0.f, 0.f, 0.f};
#pragma unroll
  for (int i = 0; i < 4; ++i)
#pragma unroll
    for (int n = 0; n < 4; ++n) acc[i][n] = zero;

  const int NK = KD / 32;
  // prefetch tile 0 into buffer 0 (wave-uniform LDS base + lane*16B)
  {
    ASYNC_COPY16(gA0, &lA[0][0] + wave * 512);
    ASYNC_COPY16(gA1, &lA[0][0] + 2048 + wave * 512);
    ASYNC_COPY16(gB0, &lB[0][0] + wave * 512);
    ASYNC_COPY16(gB1, &lB[0][0] + 2048 + wave * 512);
    gA0 += 32; gA1 += 32; gB0 += 32; gB1 += 32;
  }

  for (int kb = 0; kb < NK; ++kb) {
    const int cur = kb & 1;
    __syncthreads();  // drains prefetch of cur; all reads of cur^1 are done
    if (kb + 1 < NK) {
      ASYNC_COPY16(gA0, &lA[cur ^ 1][0] + wave * 512);
      ASYNC_COPY16(gA1, &lA[cur ^ 1][0] + 2048 + wave * 512);
      ASYNC_COPY16(gB0, &lB[cur ^ 1][0] + wave * 512);
      ASYNC_COPY16(gB1, &lB[cur ^ 1][0] + 2048 + wave * 512);
      gA0 += 32; gA1 += 32; gB0 += 32; gB1 += 32;
    }
    const u16* rdA = &lA[cur][0] + (wr * 64 + fr) * 32 + fq * 8;
    const u16* rdB = &lB[cur][0] + (wc * 64 + fr) * 32 + fq * 8;
    bf16x8 af[4], bfv[4];
#pragma unroll
    for (int i = 0; i < 4; ++i) af[i] = *(const bf16x8*)(rdA + i * 16 * 32);
#pragma unroll
    for (int n = 0; n < 4; ++n) bfv[n] = *(const bf16x8*)(rdB + n * 16 * 32);
#pragma unroll
    for (int i = 0; i < 4; ++i)
#pragma unroll
      for (int n = 0; n < 4; ++n)
        acc[i][n] = __builtin_amdgcn_mfma_f32_16x16x32_bf16(af[i], bfv[n], acc[i][n], 0, 0, 0);
  }

  // epilogue: C/D layout col=lane&15, row=(lane>>4)*4+reg
  const int colBase = n0 + wc * 64;
#pragma unroll
  for (int i = 0; i < 4; ++i) {
    const int mlBase = m0 + wr * 64 + i * 16 + fq * 4;
#pragma unroll
    for (int r = 0; r < 4; ++r) {
      const int ml = mlBase + r;
      if (ml >= cnt) continue;
      const size_t orow = (size_t)(obase + ml) * N;
      float rwgt = (STAGE == 2) ? ((z == 0) ? (1.0f / 9.0f) : slot_w[off + ml]) : 1.f;
#pragma unroll
      for (int n = 0; n < 4; ++n) {
        const int col = colBase + n * 16 + fr;
        float v = acc[i][n][r] + biasp[col];
        if (STAGE == 1) v = gelu_fast(v);
        else            v = v * rwgt;
        outH[orow + col] = f2bf(v);
      }
    }
  }
}

// ---------------------------------------------------------------------------
// K5: combine shared + 2 expert slots (bf16), then LayerNorm over O.
// ---------------------------------------------------------------------------
__global__ __launch_bounds__(256) void combine_ln2_k(
    const u16* __restrict__ sh_out, const u16* __restrict__ eout,
    const int* __restrict__ slot_of,
    const float* __restrict__ g2, const float* __restrict__ b2,
    float* __restrict__ out)
{
  const int t = blockIdx.x, tid = threadIdx.x;
  const int wave = tid >> 6, lane = tid & 63;
  __shared__ float red[8];
  const size_t s0 = (size_t)slot_of[2 * t], s1 = (size_t)slot_of[2 * t + 1];
  union { uint2 v; u16 h[4]; } a, c0, c1;
  a.v  = *(const uint2*)(sh_out + (size_t)t * 1024 + 4 * tid);
  c0.v = *(const uint2*)(eout + s0 * 1024 + 4 * tid);
  c1.v = *(const uint2*)(eout + s1 * 1024 + 4 * tid);
  float vv[4];
#pragma unroll
  for (int j = 0; j < 4; ++j) vv[j] = bf2f(a.h[j]) + bf2f(c0.h[j]) + bf2f(c1.h[j]);
  float s = vv[0] + vv[1] + vv[2] + vv[3];
  float q = vv[0] * vv[0] + vv[1] * vv[1] + vv[2] * vv[2] + vv[3] * vv[3];
#pragma unroll
  for (int o = 32; o > 0; o >>= 1) { s += __shfl_down(s, o, 64); q += __shfl_down(q, o, 64); }
  if (lane == 0) { red[wave] = s; red[4 + wave] = q; }
  __syncthreads();
  if (tid == 0) {
    float S = red[0] + red[1] + red[2] + red[3];
    float Q = red[4] + red[5] + red[6] + red[7];
    float mean = S * (1.0f / 1024.0f);
    float var = Q * (1.0f / 1024.0f) - mean * mean;
    red[0] = mean; red[1] = rsqrtf(var + 1e-5f);
  }
  __syncthreads();
  const float mean = red[0], rstd = red[1];
#pragma unroll
  for (int j = 0; j < 4; ++j) {
    int d = 4 * tid + j;
    out[(size_t)t * 1024 + d] = (vv[j] - mean) * rstd * g2[d] + b2[d];
  }
}

// ---------------------------------------------------------------------------
extern "C" void kernel_launch(void* const* d_in, const int* in_sizes, int n_in,
                              void* d_out, int out_size, void* d_ws, size_t ws_size,
                              hipStream_t stream)
{
  const float* x     = (const float*)d_in[0];
  const float* ln1_g = (const float*)d_in[1];
  const float* ln1_b = (const float*)d_in[2];
  const float* rw    = (const float*)d_in[3];
  const float* rb    = (const float*)d_in[4];
  const float* sh_w1 = (const float*)d_in[5];
  const float* sh_b1 = (const float*)d_in[6];
  const float* sh_w2 = (const float*)d_in[7];
  const float* sh_b2 = (const float*)d_in[8];
  const float* e_w1  = (const float*)d_in[9];
  const float* e_b1  = (const float*)d_in[10];
  const float* e_w2  = (const float*)d_in[11];
  const float* e_b2  = (const float*)d_in[12];
  const float* ln2_g = (const float*)d_in[13];
  const float* ln2_b = (const float*)d_in[14];
  float* out = (float*)d_out;

  char* w = (char*)d_ws;
  u16*   x_norm = (u16*)(w + 0);              //  8 MiB  [4096,1024] bf16
  u16*   hid    = (u16*)(w + (8u << 20));     // 48 MiB  [12288,2048] bf16 (shared|slots)
  u16*   outb   = (u16*)(w + (56u << 20));    // 24 MiB  [12288,1024] bf16 (shared|slots)
  u16*   w1b    = (u16*)(w + (104u << 20));   //  4 MiB  [2048,1024]  (contig with below)
  u16*   w2b    = (u16*)(w + (108u << 20));   //  4 MiB  [1024,2048]
  u16*   ew1b   = (u16*)(w + (112u << 20));   // 32 MiB  [8,2048,1024]
  u16*   ew2b   = (u16*)(w + (144u << 20));   // 32 MiB  [8,1024,2048]
  char*  meta   = w + (176u << 20);
  int*   tk_idx     = (int*)(meta);
  float* tk_w       = (float*)(meta + (32u << 10));
  int*   slot_token = (int*)(meta + (64u << 10));
  float* slot_w     = (float*)(meta + (96u << 10));
  int*   slot_of    = (int*)(meta + (128u << 10));
  int*   offs       = (int*)(meta + (160u << 10)); // 9 ints

  // all weights f32 -> bf16 in one pass (dsts are contiguous from w1b)
  cvt_all_k<<<18432, 256, 0, stream>>>(sh_w1, sh_w2, e_w1, e_w2, w1b);

  ln_router_k<<<4096, 256, 0, stream>>>(x, ln1_g, ln1_b, rw, rb, x_norm, tk_idx, tk_w);
  assign_k<<<1, 256, 0, stream>>>(tk_idx, tk_w, offs, slot_token, slot_w, slot_of);

  // FC1 (shared z=0 + experts z=1..8): -> fast GELU -> hid bf16
  gemm_fused_k<2048, 1024, 1><<<dim3(16, 32, 9), 256, 0, stream>>>(
      x_norm, w1b, ew1b, sh_b1, e_b1, hid, offs, slot_token, nullptr);
  // FC2 (shared z=0 + experts z=1..8): -> scaled bf16 -> outb
  gemm_fused_k<1024, 2048, 2><<<dim3(8, 32, 9), 256, 0, stream>>>(
      hid, w2b, ew2b, sh_b2, e_b2, outb, offs, slot_token, slot_w);

  combine_ln2_k<<<4096, 256, 0, stream>>>(outb, outb + (size_t)4096 * 1024,
                                          slot_of, ln2_g, ln2_b, out);
}